// Round 6
// baseline (221.542 us; speedup 1.0000x reference)
//
#include <hip/hip_runtime.h>
#include <hip/hip_fp16.h>
#include <stdint.h>

#define M_DIM 64
#define K_DIM 8192
#define N_DIM 28672
#define QGROUP 128
#define KSPLIT 4

typedef __attribute__((ext_vector_type(4))) float floatx4;
typedef __attribute__((ext_vector_type(8))) _Float16 halfx8;
typedef __attribute__((ext_vector_type(4))) uint32_t uintx4;

// bit_cast via memcpy (works for non-trivially-copyable HIP types)
template <typename T, typename F>
__device__ __forceinline__ T bc(F f) {
  static_assert(sizeof(T) == sizeof(F), "size mismatch");
  T t;
  __builtin_memcpy(&t, &f, sizeof(T));
  return t;
}

// p = two fp16 lanes holding (1024+nib); returns two fp16 of (nib-8)*s
// (1024+nib and 1032 are fp16-exact, same binade -> sub exact; mul RNE =
// exactly the reference's fp16 multiply)
__device__ __forceinline__ uint32_t dq_pair(uint32_t p, uint32_t s2bits) {
  __half2 v = bc<__half2>(p);
  __half2 z = bc<__half2>(0x64086408u);  // (1032, 1032)
  __half2 s = bc<__half2>(s2bits);
  return bc<uint32_t>(__hmul2(__hsub2(v, z), s));
}

// one packed dword (8 nibbles, consecutive k) -> B fragment (8 fp16) for one n
__device__ __forceinline__ halfx8 dequant8(uint32_t q, uint32_t s2bits) {
  const uint32_t MG = 0x64006400u;  // fp16(1024) in both halves
  uint32_t p01 = ((q & 0x0000000Fu) | ((q << 12) & 0x000F0000u)) | MG;
  uint32_t p23 = (((q >> 8) & 0x0000000Fu) | ((q << 4) & 0x000F0000u)) | MG;
  uint32_t p45 = (((q >> 16) & 0x0000000Fu) | ((q >> 4) & 0x000F0000u)) | MG;
  uint32_t p67 = (((q >> 24) & 0x0000000Fu) | ((q >> 12) & 0x000F0000u)) | MG;
  uintx4 r;
  r.x = dq_pair(p01, s2bits);
  r.y = dq_pair(p23, s2bits);
  r.z = dq_pair(p45, s2bits);
  r.w = dq_pair(p67, s2bits);
  return bc<halfx8>(r);
}

// Block: 256 threads = 4 waves. Block tile 64m x 256n, each wave 64m x 64n.
// Inputs A/scales/bias AND output are FLOAT32 (harness promotes the
// reference's fp16 tensors to fp32 on both sides).
// B fragments dequanted in registers from qweight (no LDS round-trip).
// A converted fp32->fp16 (exact) and staged to LDS, double-buffered 4KB.
template <int KSLICE, bool SPLIT>
__global__ __launch_bounds__(256, 2) void wq_mfma(
    const float* __restrict__ A,        // fp32, M x K (fp16-exact values)
    const int* __restrict__ qweight,    // int32, K/8 x N
    const float* __restrict__ scales,   // fp32, K/128 x N (fp16-exact)
    const float* __restrict__ bias,     // fp32, N (fp16-exact)
    float* __restrict__ part,           // KSPLIT x M x N (fp32)
    float* __restrict__ out) {          // fp32, M x N
  constexpr int STEPS = KSLICE / 32;
  constexpr int GROUPS = KSLICE / QGROUP;
  __shared__ __align__(16) _Float16 Abuf[2][4 * 64 * 8];  // [buf][kc][row][8]

  const int tid = (int)threadIdx.x;
  const int w = tid >> 6;
  const int l = tid & 63;
  const int l15 = l & 15;
  const int l4 = l >> 4;
  const int nb = (int)blockIdx.x * 256 + w * 64;
  const int kb = (int)blockIdx.y * KSLICE;
  const int ncol = nb + 4 * l15;  // lane's first n (4 consecutive)

  // A staging: thread tid -> row tid>>2, k-chunk tid&3 (8 floats = 32B)
  const int srow = tid >> 2;
  const int sc = tid & 3;
  const float* aptr = A + (size_t)srow * K_DIM + (size_t)(kb + sc * 8);
  _Float16* const lws = &Abuf[0][0] + (sc * 512 + srow * 8);
  constexpr int BUFOFF = 4 * 64 * 8;

  const int* qptr = qweight + (size_t)((kb >> 3) + l4) * N_DIM + ncol;
  const float* sptr = scales + (size_t)(kb / QGROUP) * N_DIM + ncol;

  floatx4 acc[4][4];
#pragma unroll
  for (int i = 0; i < 4; ++i)
#pragma unroll
    for (int j = 0; j < 4; ++j) acc[i][j] = (floatx4)(0.0f);

  // stage A step0 (fp32 -> fp16, exact)
  {
    floatx4 a0 = *(const floatx4*)aptr;
    floatx4 a1 = *(const floatx4*)(aptr + 4);
    halfx8 hv;
#pragma unroll
    for (int j = 0; j < 4; ++j) hv[j] = (_Float16)a0[j];
#pragma unroll
    for (int j = 0; j < 4; ++j) hv[4 + j] = (_Float16)a1[j];
    *(halfx8*)lws = hv;
  }
  aptr += 32;
  uintx4 q0 = *(const uintx4*)qptr;
  qptr += 4 * (size_t)N_DIM;
  uintx4 q1 = (STEPS > 1) ? *(const uintx4*)qptr : q0;
  qptr += 4 * (size_t)N_DIM;
  floatx4 scv = *(const floatx4*)sptr;
  sptr += N_DIM;
  __syncthreads();

  for (int g = 0; g < GROUPS; ++g) {
    uint32_t s2b[4];
#pragma unroll
    for (int d = 0; d < 4; ++d) {
      unsigned short sb = bc<unsigned short>((_Float16)scv[d]);  // exact
      s2b[d] = (uint32_t)sb * 0x10001u;                          // fp16x2 splat
    }
    floatx4 scn = scv;
    if (g + 1 < GROUPS) scn = *(const floatx4*)sptr;
    sptr += N_DIM;
#pragma unroll
    for (int tt = 0; tt < 4; ++tt) {
      const int t = g * 4 + tt;
      // A prefetch for t+1 (global fp32 -> reg; cvt+ds_write after MFMA)
      floatx4 a0, a1;
      const bool do_stage = (t + 1 < STEPS);
      if (do_stage) {
        a0 = *(const floatx4*)aptr;
        a1 = *(const floatx4*)(aptr + 4);
      }
      aptr += 32;
      uintx4 qn = q1;
      if (t + 2 < STEPS) qn = *(const uintx4*)qptr;
      qptr += 4 * (size_t)N_DIM;

      // A fragments: lane l -> row (l15 + 16*mf), k-chunk l4
      const _Float16* ab = &Abuf[t & 1][l4 * 512 + l15 * 8];
      halfx8 afr[4], bfr[4];
#pragma unroll
      for (int mf = 0; mf < 4; ++mf) afr[mf] = *(const halfx8*)(ab + mf * 128);
      bfr[0] = dequant8(q0.x, s2b[0]);
      bfr[1] = dequant8(q0.y, s2b[1]);
      bfr[2] = dequant8(q0.z, s2b[2]);
      bfr[3] = dequant8(q0.w, s2b[3]);
#pragma unroll
      for (int mf = 0; mf < 4; ++mf)
#pragma unroll
        for (int d = 0; d < 4; ++d)
          acc[mf][d] = __builtin_amdgcn_mfma_f32_16x16x32_f16(afr[mf], bfr[d],
                                                              acc[mf][d], 0, 0, 0);
      if (do_stage) {
        halfx8 hv;
#pragma unroll
        for (int j = 0; j < 4; ++j) hv[j] = (_Float16)a0[j];
#pragma unroll
        for (int j = 0; j < 4; ++j) hv[4 + j] = (_Float16)a1[j];
        *(halfx8*)(lws + ((t + 1) & 1) * BUFOFF) = hv;
      }
      q0 = q1;
      q1 = qn;
      __syncthreads();
    }
    scv = scn;
  }

  // Epilogue. C layout: row = 4*(l>>4) + reg (+16*mf), col = l&15; fragment
  // d's col c is global n = nb + 4*c + d -> 4 fragments at fixed (mf, r) are
  // 4 consecutive n. Output is FP32.
  if (SPLIT) {
    float* pbase = part + (size_t)blockIdx.y * ((size_t)M_DIM * N_DIM);
#pragma unroll
    for (int mf = 0; mf < 4; ++mf) {
#pragma unroll
      for (int r = 0; r < 4; ++r) {
        const int m = mf * 16 + l4 * 4 + r;
        floatx4 v = {acc[mf][0][r], acc[mf][1][r], acc[mf][2][r], acc[mf][3][r]};
        *(floatx4*)(pbase + (size_t)m * N_DIM + ncol) = v;
      }
    }
  } else {
    floatx4 bb = *(const floatx4*)(bias + ncol);
#pragma unroll
    for (int mf = 0; mf < 4; ++mf) {
#pragma unroll
      for (int r = 0; r < 4; ++r) {
        const int m = mf * 16 + l4 * 4 + r;
        floatx4 v = {acc[mf][0][r] + bb.x, acc[mf][1][r] + bb.y,
                     acc[mf][2][r] + bb.z, acc[mf][3][r] + bb.w};
        *(floatx4*)(out + (size_t)m * N_DIM + ncol) = v;
      }
    }
  }
}

// Sum KSPLIT fp32 partials, add fp32 bias, emit fp32.
__global__ __launch_bounds__(256) void wq_reduce(const float* __restrict__ part,
                                                 const float* __restrict__ bias,
                                                 float* __restrict__ out) {
  const int idx = (int)blockIdx.x * 256 + (int)threadIdx.x;  // over M*N/4
  const int m = idx / (N_DIM / 4);
  const int n = (idx - m * (N_DIM / 4)) * 4;
  floatx4 s = (floatx4)(0.0f);
#pragma unroll
  for (int p = 0; p < KSPLIT; ++p)
    s += *(const floatx4*)(part + ((size_t)p * M_DIM + m) * N_DIM + n);
  floatx4 bb = *(const floatx4*)(bias + n);
  s += bb;
  *(floatx4*)(out + (size_t)m * N_DIM + n) = s;
}

extern "C" void kernel_launch(void* const* d_in, const int* in_sizes, int n_in,
                              void* d_out, int out_size, void* d_ws, size_t ws_size,
                              hipStream_t stream) {
  const float* A = (const float*)d_in[0];    // fp32 (64x8192), fp16-exact
  const int* qw = (const int*)d_in[1];       // int32 (1024x28672)
  const float* sc = (const float*)d_in[2];   // fp32 (64x28672), fp16-exact
  const float* bi = (const float*)d_in[3];   // fp32 (28672), fp16-exact
  float* out = (float*)d_out;                // fp32 (64x28672)
  float* part = (float*)d_ws;

  const size_t need = (size_t)KSPLIT * M_DIM * N_DIM * sizeof(float);
  if (ws_size >= need) {
    dim3 grid(N_DIM / 256, KSPLIT);
    wq_mfma<K_DIM / KSPLIT, true><<<grid, 256, 0, stream>>>(A, qw, sc, bi, part, out);
    wq_reduce<<<(M_DIM * N_DIM / 4) / 256, 256, 0, stream>>>(part, bi, out);
  } else {
    dim3 grid(N_DIM / 256, 1);
    wq_mfma<K_DIM, false><<<grid, 256, 0, stream>>>(A, qw, sc, bi, part, out);
  }
}